// Round 6
// baseline (390.831 us; speedup 1.0000x reference)
//
#include <hip/hip_runtime.h>
#include <math.h>

#define NB    4        // graphs
#define NN    8192     // coarse nodes
#define MM    65536    // fine nodes
#define EE    131072   // edges
#define NPG   2048     // coarse per graph

typedef short short8 __attribute__((ext_vector_type(8)));
typedef float f32x4  __attribute__((ext_vector_type(4)));

static __device__ inline unsigned short f2b(float f) {
    unsigned u = __float_as_uint(f);
    u += 0x7fffu + ((u >> 16) & 1u);           // RNE
    return (unsigned short)(u >> 16);
}
static __device__ inline unsigned f2b_pack(float a, float b) {
    unsigned x = __float_as_uint(a); x += 0x7fffu + ((x >> 16) & 1u);
    unsigned y = __float_as_uint(b); y += 0x7fffu + ((y >> 16) & 1u);
    return (x >> 16) | (y & 0xffff0000u);
}
static __device__ inline short8 bc8(uint4 v) {
    union { uint4 u; short8 s; } c; c.u = v; return c.s;
}

// ---------------------------------------------------------------------------
// knn_interpolate (k=3): 1024 blocks x 256 thr; block = 64 fine nodes,
// 4 slices x 512 candidates. cp holds (-2cx,-2cy,-2cz,|c|^2) so the scan is
// 1 add + 3 fma; key = v_and_or_b32 pack (14 mantissa bits + 9-bit local idx);
// top-3 insert = 4-op f32 network (min/med3/max). Merge re-ranks the 12
// survivors with EXACT distances (u64 keys) -> selection fidelity preserved.
// ---------------------------------------------------------------------------
__global__ __launch_bounds__(256)
void k_knn(const float* __restrict__ pos, const float* __restrict__ pos_skip,
           const float* __restrict__ x, const float* __restrict__ x_skip,
           const int* __restrict__ batch_skip,
           float* __restrict__ h0, float* __restrict__ out_pos,
           float* __restrict__ out_batch)
{
    __shared__ float4 cp[NPG];                 // 32 KB (-2x,-2y,-2z,|c|^2)
    __shared__ float  pk[4][64][3];            // 3 KB partial top-3 keys
    __shared__ float  wFin[64][3];
    __shared__ int    iFin[64][3];

    int tid = threadIdx.x;
    int g = blockIdx.x >> 8;                   // 256 blocks per graph
    int cbase = g * NPG;
    for (int c = tid; c < NPG; c += 256) {
        float px = pos[(cbase + c) * 3 + 0];
        float py = pos[(cbase + c) * 3 + 1];
        float pz = pos[(cbase + c) * 3 + 2];
        cp[c] = make_float4(-2.f * px, -2.f * py, -2.f * pz, px * px + py * py + pz * pz);
    }
    __syncthreads();

    int node = tid & 63;
    int slice = tid >> 6;
    int fbase = blockIdx.x * 64;
    int f = fbase + node;
    float fx = pos_skip[f * 3 + 0], fy = pos_skip[f * 3 + 1], fz = pos_skip[f * 3 + 2];
    float fqe = fx * fx + fy * fy + fz * fz + 1e-5f;   // eps keeps d > 0 under rounding

    float k0 = 3.4028235e38f, k1 = 3.4028235e38f, k2 = 3.4028235e38f;
    const float4* cps = cp + slice * 512;
#pragma unroll 8
    for (int l = 0; l < 512; ++l) {
        float4 cc = cps[l];
        float d = fqe + cc.w;
        d = fmaf(cc.x, fx, d);
        d = fmaf(cc.y, fy, d);
        d = fmaf(cc.z, fz, d);                 // = |f-c|^2 + eps  (>0)
        float key = __uint_as_float((__float_as_uint(d) & 0xFFFFFE00u) | (unsigned)l);
        float t = fmaxf(k1, key);
        k2 = fminf(k2, t);
        k1 = __builtin_amdgcn_fmed3f(k0, k1, key);
        k0 = fminf(k0, key);
    }
    pk[slice][node][0] = k0; pk[slice][node][1] = k1; pk[slice][node][2] = k2;
    __syncthreads();

    if (tid < 64) {
        int n = tid;
        int fn = fbase + n;
        float gx = pos_skip[fn * 3 + 0], gy = pos_skip[fn * 3 + 1], gz = pos_skip[fn * 3 + 2];
        float gq = gx * gx + gy * gy + gz * gz;
        unsigned long long m0 = ~0ull, m1 = ~0ull, m2 = ~0ull;
#pragma unroll
        for (int s = 0; s < 4; ++s)
#pragma unroll
            for (int r = 0; r < 3; ++r) {
                unsigned key = __float_as_uint(pk[s][n][r]);
                int c = s * 512 + (int)(key & 511u);
                float4 cc = cp[c];
                float d = gq + cc.w;           // exact |g-c|^2 (folded -2c)
                d = fmaf(cc.x, gx, d);
                d = fmaf(cc.y, gy, d);
                d = fmaf(cc.z, gz, d);
                d = fmaxf(d, 0.f);
                unsigned long long kk = ((unsigned long long)__float_as_uint(d) << 32) | (unsigned)c;
                unsigned long long t1 = m0 > kk ? m0 : kk; m0 = m0 < kk ? m0 : kk;
                unsigned long long t2 = m1 > t1 ? m1 : t1; m1 = m1 < t1 ? m1 : t1;
                m2 = m2 < t2 ? m2 : t2;
            }
        float d0 = __uint_as_float((unsigned)(m0 >> 32));
        float d1 = __uint_as_float((unsigned)(m1 >> 32));
        float d2 = __uint_as_float((unsigned)(m2 >> 32));
        float w0 = 1.f / fmaxf(d0, 1e-16f);
        float w1 = 1.f / fmaxf(d1, 1e-16f);
        float w2 = 1.f / fmaxf(d2, 1e-16f);
        float inv = 1.f / (w0 + w1 + w2);
        wFin[n][0] = w0 * inv; wFin[n][1] = w1 * inv; wFin[n][2] = w2 * inv;
        iFin[n][0] = cbase + (int)(m0 & 2047u);
        iFin[n][1] = cbase + (int)(m1 & 2047u);
        iFin[n][2] = cbase + (int)(m2 & 2047u);
        out_pos[fn * 3 + 0] = gx; out_pos[fn * 3 + 1] = gy; out_pos[fn * 3 + 2] = gz;
        out_batch[fn] = (float)batch_skip[fn];
    }
    __syncthreads();

    // output fan-out: 4 threads per fine node
    int n2 = tid >> 2, part = tid & 3;
    int f2 = fbase + n2;
    float4* h04 = (float4*)(h0 + (size_t)f2 * 32);
    if (part < 2) {
        const float4* x4 = (const float4*)x;
        float w0 = wFin[n2][0], w1 = wFin[n2][1], w2 = wFin[n2][2];
        int a0 = iFin[n2][0] * 4, a1 = iFin[n2][1] * 4, a2 = iFin[n2][2] * 4;
#pragma unroll
        for (int j = 0; j < 2; ++j) {
            int cj = part * 2 + j;
            float4 v0 = x4[a0 + cj], v1 = x4[a1 + cj], v2 = x4[a2 + cj];
            float4 r;
            r.x = w0 * v0.x + w1 * v1.x + w2 * v2.x;
            r.y = w0 * v0.y + w1 * v1.y + w2 * v2.y;
            r.z = w0 * v0.z + w1 * v1.z + w2 * v2.z;
            r.w = w0 * v0.w + w1 * v1.w + w2 * v2.w;
            h04[cj] = r;
        }
    } else {
        const float4* xs4 = (const float4*)x_skip;
#pragma unroll
        for (int j = 0; j < 2; ++j) {
            int cj = (part - 2) * 2 + j;
            h04[4 + cj] = xs4[f2 * 4 + cj];
        }
    }
}

// ---------------------------------------------------------------------------
// token prep 1: Kt/Vt = gt @ W^T + b + pe   -> KtVt [B][2][16][64]
// ---------------------------------------------------------------------------
__global__ __launch_bounds__(128)
void k_tokens1(const float* __restrict__ gt,
               const float* __restrict__ Wk_w, const float* __restrict__ Wk_b,
               const float* __restrict__ Wv_w, const float* __restrict__ Wv_b,
               float* __restrict__ KtVt)
{
    int b = blockIdx.x >> 4;
    int t = blockIdx.x & 15;
    int which = threadIdx.x >> 6;
    int d = threadIdx.x & 63;
    const float* W = which ? Wv_w : Wk_w;
    const float* bias = which ? Wv_b : Wk_b;
    const float4* row = (const float4*)(gt + (size_t)(b * 16 + t) * 1024);
    const float4* wr = (const float4*)(W + (size_t)d * 1024);
    float acc = 0.f;
    for (int c = 0; c < 256; ++c) {
        float4 a = row[c], w = wr[c];
        acc += a.x * w.x; acc += a.y * w.y; acc += a.z * w.z; acc += a.w * w.w;
    }
    int i2 = d >> 1;
    float dv = expf((float)(2 * i2) * (-0.14391156831212787f)); // -ln(10000)/64
    float ang = (float)t * dv;
    float pe = (d & 1) ? cosf(ang) : sinf(ang);
    KtVt[((size_t)(b * 2 + which) * 16 + t) * 64 + d] = acc + bias[d] + pe;
}

// ---------------------------------------------------------------------------
// token prep 2 (per graph): k/v head proj; V2 = out_w-folded v heads into LDS;
// emits Mfold[g][th=t*4+h][4] and v2f[g] (V2^T, bf16 A-frag layout).
// ---------------------------------------------------------------------------
__global__ __launch_bounds__(256)
void k_tokens2(const float* __restrict__ KtVt,
               const float* __restrict__ in_proj_w, const float* __restrict__ in_proj_b,
               const float* __restrict__ out_w,
               const float* __restrict__ Wq_w, const float* __restrict__ Wq_b,
               float* __restrict__ Mfold, uint4* __restrict__ v2fG)
{
    int b = blockIdx.x;
    int tid = threadIdx.x;
    __shared__ float KtL[1024], VtL[1024], vv[1024], kproj[1024];
    __shared__ float v2L[4096];
    __shared__ float qWs[192], qbs[64];
    for (int idx = tid; idx < 1024; idx += 256) {
        KtL[idx] = KtVt[(size_t)(b * 2 + 0) * 1024 + idx];
        VtL[idx] = KtVt[(size_t)(b * 2 + 1) * 1024 + idx];
    }
    __syncthreads();
    for (int idx = tid; idx < 2048; idx += 256) {
        int which = idx >> 10; int td = idx & 1023; int t = td >> 6; int j = td & 63;
        int r = (which ? 128 : 64) + j;
        const float* w = in_proj_w + (size_t)r * 64;
        const float* src = which ? VtL : KtL;
        float acc = in_proj_b[r];
#pragma unroll 8
        for (int dd = 0; dd < 64; ++dd) acc += src[t * 64 + dd] * w[dd];
        if (which) vv[t * 64 + j] = acc;
        else kproj[t * 64 + j] = acc;
    }
    // qW/qb2 fold (graph-independent, computed by every block; cheap)
    for (int idx = tid; idx < 192; idx += 256) {
        int c = idx >> 6; int j = idx & 63;
        float acc = 0.f;
        for (int dd = 0; dd < 64; ++dd) acc += in_proj_w[(size_t)j * 64 + dd] * Wq_w[dd * 3 + c];
        qWs[c * 64 + j] = acc;
    }
    for (int j = tid; j < 64; j += 256) {
        float acc = in_proj_b[j];
        for (int dd = 0; dd < 64; ++dd) acc += in_proj_w[(size_t)j * 64 + dd] * Wq_b[dd];
        qbs[j] = acc;
    }
    __syncthreads();
    // V2 rows (th = t*4+h) into LDS
    for (int idx = tid; idx < 4096; idx += 256) {
        int jo = idx & 63; int th2 = idx >> 6; int h = th2 & 3; int t = th2 >> 2;
        float acc = 0.f;
#pragma unroll
        for (int dd = 0; dd < 16; ++dd)
            acc += vv[t * 64 + h * 16 + dd] * out_w[(size_t)jo * 64 + h * 16 + dd];
        v2L[(t * 4 + h) * 64 + jo] = acc;
    }
    // Mfold: thread = (th, c)
    {
        int th = tid >> 2, c = tid & 3;
        int t = th >> 2, h = th & 3;
        float acc = 0.f;
#pragma unroll
        for (int dd = h * 16; dd < h * 16 + 16; ++dd) {
            float w = (c == 0) ? qWs[dd] : (c == 1) ? qWs[64 + dd]
                    : (c == 2) ? qWs[128 + dd] : qbs[dd];
            acc += w * kproj[t * 64 + dd];
        }
        Mfold[((size_t)b * 64 + th) * 4 + c] = 0.25f * acc;
    }
    __syncthreads();
    // v2f pack: A-frag bf16, element j: th = step*32 + quad*8 + j, outdim = mi*16 + col
    for (int it = tid; it < 512; it += 256) {
        int lane = it & 63, fi = it >> 6;
        int mi = fi >> 1, step = fi & 1;
        int outd = mi * 16 + (lane & 15);
        int th0 = step * 32 + (lane >> 4) * 8;
        uint4 v;
        v.x = f2b_pack(v2L[(th0 + 0) * 64 + outd], v2L[(th0 + 1) * 64 + outd]);
        v.y = f2b_pack(v2L[(th0 + 2) * 64 + outd], v2L[(th0 + 3) * 64 + outd]);
        v.z = f2b_pack(v2L[(th0 + 4) * 64 + outd], v2L[(th0 + 5) * 64 + outd]);
        v.w = f2b_pack(v2L[(th0 + 6) * 64 + outd], v2L[(th0 + 7) * 64 + outd]);
        v2fG[((size_t)b * 8 + fi) * 64 + lane] = v;
    }
}

// ---------------------------------------------------------------------------
// per-edge cross attention, MFMA PV (unchanged from round 5)
// ---------------------------------------------------------------------------
__global__ __launch_bounds__(256)
void k_edge_attn(const float* __restrict__ ps, const int* __restrict__ ei,
                 const float* __restrict__ Mfold, const uint4* __restrict__ v2f,
                 const float* __restrict__ ob,
                 unsigned short* __restrict__ Pf, float* __restrict__ cnt)
{
    __shared__ unsigned attL[4 * 64 * 34];     // 34.8 KB; per-wave 64x34-dword slab
    int tid = threadIdx.x;
    int wave = tid >> 6, lane = tid & 63, q = lane >> 4, c15 = lane & 15;
    int g = blockIdx.x >> 7;                   // 128 blocks per graph
    int e = blockIdx.x * 256 + tid;
    int s = ei[e], d = ei[EE + e];
    atomicAdd(&cnt[d], 1.f);
    float sx = ps[s * 3], sy = ps[s * 3 + 1], sz = ps[s * 3 + 2];
    float dx = ps[d * 3], dy = ps[d * 3 + 1], dz = ps[d * 3 + 2];
    float px = dx - sx, py = dy - sy, pz = dz - sz;
    float ex = 0.5f * (dx + sx), ey = 0.5f * (dy + sy), ez = 0.5f * (dz + sz);

    const float4* Mg = (const float4*)Mfold + (size_t)g * 64;
    float sc[64];
#pragma unroll
    for (int th = 0; th < 64; ++th) {
        float4 m = Mg[th];
        sc[th] = ex * m.x + ey * m.y + ez * m.z + m.w;
    }
#pragma unroll
    for (int h = 0; h < 4; ++h) {
        float mx = sc[h];
#pragma unroll
        for (int t = 1; t < 16; ++t) mx = fmaxf(mx, sc[t * 4 + h]);
        float ssum = 0.f;
#pragma unroll
        for (int t = 0; t < 16; ++t) {
            float eo = expf(sc[t * 4 + h] - mx);
            sc[t * 4 + h] = eo; ssum += eo;
        }
        float inv = 1.f / ssum;
#pragma unroll
        for (int t = 0; t < 16; ++t) sc[t * 4 + h] *= inv;
    }
    unsigned* slab = attL + wave * 64 * 34;
#pragma unroll
    for (int k = 0; k < 16; ++k) {
        uint2 v;
        v.x = f2b_pack(sc[4 * k + 0], sc[4 * k + 1]);
        v.y = f2b_pack(sc[4 * k + 2], sc[4 * k + 3]);
        *(uint2*)&slab[lane * 34 + 2 * k] = v;
    }
    __syncthreads();

    uint4 v2a[4][2];
#pragma unroll
    for (int mi = 0; mi < 4; ++mi)
#pragma unroll
        for (int st = 0; st < 2; ++st)
            v2a[mi][st] = v2f[((size_t)g * 8 + mi * 2 + st) * 64 + lane];

    f32x4 acc[4][4];
#pragma unroll
    for (int mi = 0; mi < 4; ++mi)
#pragma unroll
        for (int nt = 0; nt < 4; ++nt) acc[mi][nt] = (f32x4){0.f, 0.f, 0.f, 0.f};

#pragma unroll
    for (int nt = 0; nt < 4; ++nt) {
        const unsigned* rb = &slab[(nt * 16 + c15) * 34];
        uint4 b0 = *(const uint4*)&rb[q * 4];
        uint4 b1 = *(const uint4*)&rb[16 + q * 4];
#pragma unroll
        for (int mi = 0; mi < 4; ++mi) {
            acc[mi][nt] = __builtin_amdgcn_mfma_f32_16x16x32_bf16(bc8(v2a[mi][0]), bc8(b0), acc[mi][nt], 0, 0, 0);
            acc[mi][nt] = __builtin_amdgcn_mfma_f32_16x16x32_bf16(bc8(v2a[mi][1]), bc8(b1), acc[mi][nt], 0, 0, 0);
        }
    }
    __syncthreads();

    float4 obv[4];
#pragma unroll
    for (int mi = 0; mi < 4; ++mi) obv[mi] = *(const float4*)(ob + mi * 16 + q * 4);
#pragma unroll
    for (int mi = 0; mi < 4; ++mi)
#pragma unroll
        for (int nt = 0; nt < 4; ++nt) {
            f32x4 a = acc[mi][nt];
            uint2 v;
            v.x = f2b_pack(a[0] + obv[mi].x, a[1] + obv[mi].y);
            v.y = f2b_pack(a[2] + obv[mi].z, a[3] + obv[mi].w);
            *(uint2*)&slab[(nt * 16 + c15) * 34 + mi * 8 + q * 2] = v;
        }
    __syncthreads();

    uint4* Pf4 = (uint4*)Pf;
#pragma unroll
    for (int et = 0; et < 4; ++et) {
        int etg = blockIdx.x * 16 + wave * 4 + et;
#pragma unroll
        for (int st = 0; st < 2; ++st) {
            uint4 w = *(const uint4*)&slab[(et * 16 + c15) * 34 + st * 16 + q * 4];
            Pf4[((size_t)etg * 3 + st) * 64 + lane] = w;
        }
    }
    int et2 = e >> 4, eL = e & 15;
    size_t tb = ((size_t)(et2 * 3 + 2) * 64 + 0 * 16 + eL) * 8;
    uint2 t0; t0.x = f2b_pack(px, py); t0.y = f2b_pack(pz, 1.0f);
    *(uint2*)(Pf + tb) = t0;
    uint2 z2; z2.x = 0u; z2.y = 0u;
    *(uint2*)(Pf + tb + 4) = z2;
#pragma unroll
    for (int quad = 1; quad < 4; ++quad) {
        size_t zb = ((size_t)(et2 * 3 + 2) * 64 + quad * 16 + eL) * 8;
        uint4 z4; z4.x = 0u; z4.y = 0u; z4.z = 0u; z4.w = 0u;
        *(uint4*)(Pf + zb) = z4;
    }
}

// ---------------------------------------------------------------------------
// fused repack of all 3 layers' nn_w/nn_b -> bf16 B-fragment streams
// ---------------------------------------------------------------------------
static __device__ inline void repack_one(const float* __restrict__ nw,
                                         const float* __restrict__ nb,
                                         unsigned short* __restrict__ Wf, int idx)
{
    int jj = idx & 7;
    int lane = (idx >> 3) & 63;
    int rest = idx >> 9;
    int s = rest % 3;
    int jt = rest / 3;
    int j = jt * 16 + (lane & 15);
    int k = s * 32 + (lane >> 4) * 8 + jj;
    float v;
    if (k < 64)       v = nw[(size_t)j * 67 + 3 + k];
    else if (k < 67)  v = nw[(size_t)j * 67 + (k - 64)];
    else if (k == 67) v = nb[j];
    else              v = 0.f;
    Wf[idx] = f2b(v);
}

__global__ __launch_bounds__(256)
void k_repackAll(const float* __restrict__ nw0, const float* __restrict__ nb0,
                 const float* __restrict__ nw1, const float* __restrict__ nb1,
                 const float* __restrict__ nw2, const float* __restrict__ nb2,
                 unsigned short* __restrict__ Wf0, unsigned short* __restrict__ Wf1,
                 unsigned short* __restrict__ Wf2)
{
    int idx = blockIdx.x * 256 + threadIdx.x;
    if (idx < 98304)        repack_one(nw0, nb0, Wf0, idx);
    else if (idx < 196608)  repack_one(nw1, nb1, Wf1, idx - 98304);
    else                    repack_one(nw2, nb2, Wf2, idx - 196608);
}

// ---------------------------------------------------------------------------
// MFMA edge pass: 256 edges/block, per wave 64 edges (4 A-frag sets) -> each
// Wf element loaded once serves 64 edges (halves the L2 weight stream vs 32).
// CO=32: hv LDS reads hoisted across the jt-pair sharing the same i.
// ---------------------------------------------------------------------------
template<int CO>
__global__ __launch_bounds__(256, 2)
void k_conv_mfma(const uint4* __restrict__ Pf, const float* __restrict__ hin,
                 const int* __restrict__ ei, const uint4* __restrict__ Wf,
                 float* __restrict__ aggr)
{
    constexpr int NPAR = CO / 16;       // 2 or 1
    __shared__ float hL[256 * 36];      // 36.9 KB, stride 36 floats
    __shared__ int sL[256];
    __shared__ int dL[256];

    int tid = threadIdx.x;
    int e0 = blockIdx.x * 256;
    sL[tid] = ei[e0 + tid];
    dL[tid] = ei[EE + e0 + tid];
    __syncthreads();
    for (int idx = tid; idx < 2048; idx += 256) {
        int row = idx >> 3, c = idx & 7;
        const float4* hr = (const float4*)(hin + (size_t)sL[row] * 32);
        *(float4*)&hL[row * 36 + c * 4] = hr[c];
    }
    __syncthreads();

    int wave = tid >> 6, lane = tid & 63, quad = lane >> 4, col = lane & 15;

    uint4 a[4][3];
    int et0 = blockIdx.x * 16 + wave * 4;
#pragma unroll
    for (int st = 0; st < 4; ++st)
#pragma unroll
        for (int s = 0; s < 3; ++s)
            a[st][s] = Pf[((size_t)(et0 + st) * 3 + s) * 64 + lane];

    float msg[4][NPAR][4];
#pragma unroll
    for (int st = 0; st < 4; ++st)
#pragma unroll
        for (int p = 0; p < NPAR; ++p)
#pragma unroll
            for (int r = 0; r < 4; ++r) msg[st][p][r] = 0.f;

    for (int i = 0; i < 32; ++i) {
        if (CO == 16 && i >= 32) break;       // (CO=16 uses i<32 too; JT=32)
        float hv[4][4];
#pragma unroll
        for (int st = 0; st < 4; ++st)
#pragma unroll
            for (int r = 0; r < 4; ++r)
                hv[st][r] = hL[(wave * 64 + st * 16 + quad * 4 + r) * 36 + i];
#pragma unroll
        for (int par = 0; par < NPAR; ++par) {
            int jt = (CO == 32) ? (i * 2 + par) : i;
            uint4 b0 = Wf[((size_t)jt * 3 + 0) * 64 + lane];
            uint4 b1 = Wf[((size_t)jt * 3 + 1) * 64 + lane];
            uint4 b2 = Wf[((size_t)jt * 3 + 2) * 64 + lane];
#pragma unroll
            for (int st = 0; st < 4; ++st) {
                f32x4 c = {0.f, 0.f, 0.f, 0.f};
                c = __builtin_amdgcn_mfma_f32_16x16x32_bf16(bc8(a[st][0]), bc8(b0), c, 0, 0, 0);
                c = __builtin_amdgcn_mfma_f32_16x16x32_bf16(bc8(a[st][1]), bc8(b1), c, 0, 0, 0);
                c = __builtin_amdgcn_mfma_f32_16x16x32_bf16(bc8(a[st][2]), bc8(b2), c, 0, 0, 0);
#pragma unroll
                for (int r = 0; r < 4; ++r)
                    msg[st][par][r] += hv[st][r] * fmaxf(c[r], 0.f);
            }
        }
    }

#pragma unroll
    for (int st = 0; st < 4; ++st)
#pragma unroll
        for (int r = 0; r < 4; ++r) {
            int dv = dL[wave * 64 + st * 16 + quad * 4 + r];
#pragma unroll
            for (int p = 0; p < NPAR; ++p)
                atomicAdd(&aggr[(size_t)dv * CO + p * 16 + col], msg[st][p][r]);
        }
}

// ---------------------------------------------------------------------------
// node update: h' = relu(aggr/cnt + h @ root + bias); zeroes aggr for the
// next layer's atomic pass.
// ---------------------------------------------------------------------------
template<int CO>
__global__ __launch_bounds__(256)
void k_update(float* __restrict__ aggr, const float* __restrict__ cnt,
              const float* __restrict__ hin, const float* __restrict__ root,
              const float* __restrict__ bias, float* __restrict__ hout)
{
    __shared__ float rL[32 * CO];
    __shared__ float bL[CO];
    int tid = threadIdx.x;
    for (int idx = tid; idx < 32 * CO; idx += 256) rL[idx] = root[idx];
    if (tid < CO) bL[tid] = bias[tid];
    __syncthreads();
    int gid = blockIdx.x * 256 + tid;
    int v = gid / CO;
    int o = gid % CO;
    float acc = aggr[gid] / fmaxf(cnt[v], 1.f) + bL[o];
    aggr[gid] = 0.f;                    // prep next layer's scatter
    const float* hr = hin + (size_t)v * 32;
#pragma unroll
    for (int i = 0; i < 32; ++i) acc += hr[i] * rL[i * CO + o];
    hout[gid] = fmaxf(acc, 0.f);
}

// ---------------------------------------------------------------------------
extern "C" void kernel_launch(void* const* d_in, const int* in_sizes, int n_in,
                              void* d_out, int out_size, void* d_ws, size_t ws_size,
                              hipStream_t stream)
{
    const float* x          = (const float*)d_in[0];
    const float* pos        = (const float*)d_in[1];
    const float* x_skip     = (const float*)d_in[3];
    const float* pos_skip   = (const float*)d_in[4];
    const int*   batch_skip = (const int*)  d_in[5];
    const int*   ei         = (const int*)  d_in[6];
    const float* gt         = (const float*)d_in[7];
    const float* Wq_w       = (const float*)d_in[8];
    const float* Wq_b       = (const float*)d_in[9];
    const float* Wk_w       = (const float*)d_in[10];
    const float* Wk_b       = (const float*)d_in[11];
    const float* Wv_w       = (const float*)d_in[12];
    const float* Wv_b       = (const float*)d_in[13];
    const float* in_proj_w  = (const float*)d_in[14];
    const float* in_proj_b  = (const float*)d_in[15];
    const float* out_w      = (const float*)d_in[16];
    const float* out_b      = (const float*)d_in[17];
    const float* nn_w0 = (const float*)d_in[18]; const float* nn_b0 = (const float*)d_in[19];
    const float* root0 = (const float*)d_in[20]; const float* bias0 = (const float*)d_in[21];
    const float* nn_w1 = (const float*)d_in[22]; const float* nn_b1 = (const float*)d_in[23];
    const float* root1 = (const float*)d_in[24]; const float* bias1 = (const float*)d_in[25];
    const float* nn_w2 = (const float*)d_in[26]; const float* nn_b2 = (const float*)d_in[27];
    const float* root2 = (const float*)d_in[28]; const float* bias2 = (const float*)d_in[29];

    char* wsb = (char*)d_ws;
    size_t off = 0;
    auto carve = [&](size_t bytes) { char* p = wsb + off; off += (bytes + 255) & ~(size_t)255; return p; };
    float* aggr = (float*)carve((size_t)MM * 32 * 4);   // aggr then cnt: one memset
    float* cnt  = (float*)carve((size_t)MM * 4);
    float* hA   = (float*)carve((size_t)MM * 32 * 4);
    float* hB   = (float*)carve((size_t)MM * 32 * 4);
    unsigned short* Pf  = (unsigned short*)carve((size_t)EE * 96 * 2);
    unsigned short* Wf0 = (unsigned short*)carve((size_t)1024 * 96 * 2);
    unsigned short* Wf1 = (unsigned short*)carve((size_t)1024 * 96 * 2);
    unsigned short* Wf2 = (unsigned short*)carve((size_t)512 * 96 * 2);
    float* Mfold = (float*)carve((size_t)NB * 64 * 4 * 4);
    uint4* v2f   = (uint4*)carve((size_t)NB * 8 * 64 * 16);
    float* KtVt  = (float*)carve((size_t)NB * 2 * 16 * 64 * 4);

    float* h_final   = (float*)d_out;                 // [M,16]
    float* out_pos   = (float*)d_out + (size_t)MM * 16;
    float* out_batch = (float*)d_out + (size_t)MM * 19;

    // one memset covers aggr (MM*32) + cnt (MM) — adjacent carves
    hipMemsetAsync(aggr, 0, ((size_t)MM * 32 + MM) * sizeof(float), stream);

    k_tokens1<<<64, 128, 0, stream>>>(gt, Wk_w, Wk_b, Wv_w, Wv_b, KtVt);
    k_tokens2<<<NB, 256, 0, stream>>>(KtVt, in_proj_w, in_proj_b, out_w, Wq_w, Wq_b,
                                      Mfold, v2f);
    k_knn<<<MM / 64, 256, 0, stream>>>(pos, pos_skip, x, x_skip, batch_skip,
                                       hA, out_pos, out_batch);
    k_edge_attn<<<EE / 256, 256, 0, stream>>>(pos_skip, ei, Mfold, v2f, out_b,
                                              Pf, cnt);
    k_repackAll<<<960, 256, 0, stream>>>(nn_w0, nn_b0, nn_w1, nn_b1, nn_w2, nn_b2,
                                         Wf0, Wf1, Wf2);

    // layer 0: hA -> hB   (update zeroes aggr for layer 1)
    k_conv_mfma<32><<<EE / 256, 256, 0, stream>>>((const uint4*)Pf, hA, ei, (const uint4*)Wf0, aggr);
    k_update<32><<<(MM * 32) / 256, 256, 0, stream>>>(aggr, cnt, hA, root0, bias0, hB);
    // layer 1: hB -> hA   (update zeroes aggr for layer 2)
    k_conv_mfma<32><<<EE / 256, 256, 0, stream>>>((const uint4*)Pf, hB, ei, (const uint4*)Wf1, aggr);
    k_update<32><<<(MM * 32) / 256, 256, 0, stream>>>(aggr, cnt, hB, root1, bias1, hA);
    // layer 2: hA -> d_out
    k_conv_mfma<16><<<EE / 256, 256, 0, stream>>>((const uint4*)Pf, hA, ei, (const uint4*)Wf2, aggr);
    k_update<16><<<(MM * 16) / 256, 256, 0, stream>>>(aggr, cnt, hA, root2, bias2, h_final);
}

// Round 7
// 362.906 us; speedup vs baseline: 1.0769x; 1.0769x over previous
//
#include <hip/hip_runtime.h>
#include <math.h>

#define NB    4        // graphs
#define NN    8192     // coarse nodes
#define MM    65536    // fine nodes
#define EE    131072   // edges
#define NPG   2048     // coarse per graph

typedef short short8 __attribute__((ext_vector_type(8)));
typedef float f32x4  __attribute__((ext_vector_type(4)));

static __device__ inline unsigned short f2b(float f) {
    unsigned u = __float_as_uint(f);
    u += 0x7fffu + ((u >> 16) & 1u);           // RNE
    return (unsigned short)(u >> 16);
}
static __device__ inline unsigned f2b_pack(float a, float b) {
    unsigned x = __float_as_uint(a); x += 0x7fffu + ((x >> 16) & 1u);
    unsigned y = __float_as_uint(b); y += 0x7fffu + ((y >> 16) & 1u);
    return (x >> 16) | (y & 0xffff0000u);
}
static __device__ inline short8 bc8(uint4 v) {
    union { uint4 u; short8 s; } c; c.u = v; return c.s;
}

// ---------------------------------------------------------------------------
// knn_interpolate (k=3): 1024 blocks x 256 thr; block = 64 fine nodes,
// 4 slices x 512 candidates; branchless f32 top-3 (min/med3/max); exact
// u64 re-rank of the 12 survivors. (unchanged from round 6)
// ---------------------------------------------------------------------------
__global__ __launch_bounds__(256)
void k_knn(const float* __restrict__ pos, const float* __restrict__ pos_skip,
           const float* __restrict__ x, const float* __restrict__ x_skip,
           const int* __restrict__ batch_skip,
           float* __restrict__ h0, float* __restrict__ out_pos,
           float* __restrict__ out_batch)
{
    __shared__ float4 cp[NPG];                 // 32 KB (-2x,-2y,-2z,|c|^2)
    __shared__ float  pk[4][64][3];            // 3 KB partial top-3 keys
    __shared__ float  wFin[64][3];
    __shared__ int    iFin[64][3];

    int tid = threadIdx.x;
    int g = blockIdx.x >> 8;                   // 256 blocks per graph
    int cbase = g * NPG;
    for (int c = tid; c < NPG; c += 256) {
        float px = pos[(cbase + c) * 3 + 0];
        float py = pos[(cbase + c) * 3 + 1];
        float pz = pos[(cbase + c) * 3 + 2];
        cp[c] = make_float4(-2.f * px, -2.f * py, -2.f * pz, px * px + py * py + pz * pz);
    }
    __syncthreads();

    int node = tid & 63;
    int slice = tid >> 6;
    int fbase = blockIdx.x * 64;
    int f = fbase + node;
    float fx = pos_skip[f * 3 + 0], fy = pos_skip[f * 3 + 1], fz = pos_skip[f * 3 + 2];
    float fqe = fx * fx + fy * fy + fz * fz + 1e-5f;

    float k0 = 3.4028235e38f, k1 = 3.4028235e38f, k2 = 3.4028235e38f;
    const float4* cps = cp + slice * 512;
#pragma unroll 8
    for (int l = 0; l < 512; ++l) {
        float4 cc = cps[l];
        float d = fqe + cc.w;
        d = fmaf(cc.x, fx, d);
        d = fmaf(cc.y, fy, d);
        d = fmaf(cc.z, fz, d);
        float key = __uint_as_float((__float_as_uint(d) & 0xFFFFFE00u) | (unsigned)l);
        float t = fmaxf(k1, key);
        k2 = fminf(k2, t);
        k1 = __builtin_amdgcn_fmed3f(k0, k1, key);
        k0 = fminf(k0, key);
    }
    pk[slice][node][0] = k0; pk[slice][node][1] = k1; pk[slice][node][2] = k2;
    __syncthreads();

    if (tid < 64) {
        int n = tid;
        int fn = fbase + n;
        float gx = pos_skip[fn * 3 + 0], gy = pos_skip[fn * 3 + 1], gz = pos_skip[fn * 3 + 2];
        float gq = gx * gx + gy * gy + gz * gz;
        unsigned long long m0 = ~0ull, m1 = ~0ull, m2 = ~0ull;
#pragma unroll
        for (int s = 0; s < 4; ++s)
#pragma unroll
            for (int r = 0; r < 3; ++r) {
                unsigned key = __float_as_uint(pk[s][n][r]);
                int c = s * 512 + (int)(key & 511u);
                float4 cc = cp[c];
                float d = gq + cc.w;
                d = fmaf(cc.x, gx, d);
                d = fmaf(cc.y, gy, d);
                d = fmaf(cc.z, gz, d);
                d = fmaxf(d, 0.f);
                unsigned long long kk = ((unsigned long long)__float_as_uint(d) << 32) | (unsigned)c;
                unsigned long long t1 = m0 > kk ? m0 : kk; m0 = m0 < kk ? m0 : kk;
                unsigned long long t2 = m1 > t1 ? m1 : t1; m1 = m1 < t1 ? m1 : t1;
                m2 = m2 < t2 ? m2 : t2;
            }
        float d0 = __uint_as_float((unsigned)(m0 >> 32));
        float d1 = __uint_as_float((unsigned)(m1 >> 32));
        float d2 = __uint_as_float((unsigned)(m2 >> 32));
        float w0 = 1.f / fmaxf(d0, 1e-16f);
        float w1 = 1.f / fmaxf(d1, 1e-16f);
        float w2 = 1.f / fmaxf(d2, 1e-16f);
        float inv = 1.f / (w0 + w1 + w2);
        wFin[n][0] = w0 * inv; wFin[n][1] = w1 * inv; wFin[n][2] = w2 * inv;
        iFin[n][0] = cbase + (int)(m0 & 2047u);
        iFin[n][1] = cbase + (int)(m1 & 2047u);
        iFin[n][2] = cbase + (int)(m2 & 2047u);
        out_pos[fn * 3 + 0] = gx; out_pos[fn * 3 + 1] = gy; out_pos[fn * 3 + 2] = gz;
        out_batch[fn] = (float)batch_skip[fn];
    }
    __syncthreads();

    int n2 = tid >> 2, part = tid & 3;
    int f2 = fbase + n2;
    float4* h04 = (float4*)(h0 + (size_t)f2 * 32);
    if (part < 2) {
        const float4* x4 = (const float4*)x;
        float w0 = wFin[n2][0], w1 = wFin[n2][1], w2 = wFin[n2][2];
        int a0 = iFin[n2][0] * 4, a1 = iFin[n2][1] * 4, a2 = iFin[n2][2] * 4;
#pragma unroll
        for (int j = 0; j < 2; ++j) {
            int cj = part * 2 + j;
            float4 v0 = x4[a0 + cj], v1 = x4[a1 + cj], v2 = x4[a2 + cj];
            float4 r;
            r.x = w0 * v0.x + w1 * v1.x + w2 * v2.x;
            r.y = w0 * v0.y + w1 * v1.y + w2 * v2.y;
            r.z = w0 * v0.z + w1 * v1.z + w2 * v2.z;
            r.w = w0 * v0.w + w1 * v1.w + w2 * v2.w;
            h04[cj] = r;
        }
    } else {
        const float4* xs4 = (const float4*)x_skip;
#pragma unroll
        for (int j = 0; j < 2; ++j) {
            int cj = (part - 2) * 2 + j;
            h04[4 + cj] = xs4[f2 * 4 + cj];
        }
    }
}

// ---------------------------------------------------------------------------
// token prep 1: Kt/Vt = gt @ W^T + b + pe   -> KtVt [B][2][16][64]
// ---------------------------------------------------------------------------
__global__ __launch_bounds__(128)
void k_tokens1(const float* __restrict__ gt,
               const float* __restrict__ Wk_w, const float* __restrict__ Wk_b,
               const float* __restrict__ Wv_w, const float* __restrict__ Wv_b,
               float* __restrict__ KtVt)
{
    int b = blockIdx.x >> 4;
    int t = blockIdx.x & 15;
    int which = threadIdx.x >> 6;
    int d = threadIdx.x & 63;
    const float* W = which ? Wv_w : Wk_w;
    const float* bias = which ? Wv_b : Wk_b;
    const float4* row = (const float4*)(gt + (size_t)(b * 16 + t) * 1024);
    const float4* wr = (const float4*)(W + (size_t)d * 1024);
    float acc = 0.f;
    for (int c = 0; c < 256; ++c) {
        float4 a = row[c], w = wr[c];
        acc += a.x * w.x; acc += a.y * w.y; acc += a.z * w.z; acc += a.w * w.w;
    }
    int i2 = d >> 1;
    float dv = expf((float)(2 * i2) * (-0.14391156831212787f)); // -ln(10000)/64
    float ang = (float)t * dv;
    float pe = (d & 1) ? cosf(ang) : sinf(ang);
    KtVt[((size_t)(b * 2 + which) * 16 + t) * 64 + d] = acc + bias[d] + pe;
}

// ---------------------------------------------------------------------------
// token prep 2 (per graph): k/v head proj; V2 = out_w-folded v heads into LDS;
// emits Mfold[g][th=t*4+h][4] and v2f[g] (V2^T, bf16 A-frag layout).
// ---------------------------------------------------------------------------
__global__ __launch_bounds__(256)
void k_tokens2(const float* __restrict__ KtVt,
               const float* __restrict__ in_proj_w, const float* __restrict__ in_proj_b,
               const float* __restrict__ out_w,
               const float* __restrict__ Wq_w, const float* __restrict__ Wq_b,
               float* __restrict__ Mfold, uint4* __restrict__ v2fG)
{
    int b = blockIdx.x;
    int tid = threadIdx.x;
    __shared__ float KtL[1024], VtL[1024], vv[1024], kproj[1024];
    __shared__ float v2L[4096];
    __shared__ float qWs[192], qbs[64];
    for (int idx = tid; idx < 1024; idx += 256) {
        KtL[idx] = KtVt[(size_t)(b * 2 + 0) * 1024 + idx];
        VtL[idx] = KtVt[(size_t)(b * 2 + 1) * 1024 + idx];
    }
    __syncthreads();
    for (int idx = tid; idx < 2048; idx += 256) {
        int which = idx >> 10; int td = idx & 1023; int t = td >> 6; int j = td & 63;
        int r = (which ? 128 : 64) + j;
        const float* w = in_proj_w + (size_t)r * 64;
        const float* src = which ? VtL : KtL;
        float acc = in_proj_b[r];
#pragma unroll 8
        for (int dd = 0; dd < 64; ++dd) acc += src[t * 64 + dd] * w[dd];
        if (which) vv[t * 64 + j] = acc;
        else kproj[t * 64 + j] = acc;
    }
    for (int idx = tid; idx < 192; idx += 256) {
        int c = idx >> 6; int j = idx & 63;
        float acc = 0.f;
        for (int dd = 0; dd < 64; ++dd) acc += in_proj_w[(size_t)j * 64 + dd] * Wq_w[dd * 3 + c];
        qWs[c * 64 + j] = acc;
    }
    for (int j = tid; j < 64; j += 256) {
        float acc = in_proj_b[j];
        for (int dd = 0; dd < 64; ++dd) acc += in_proj_w[(size_t)j * 64 + dd] * Wq_b[dd];
        qbs[j] = acc;
    }
    __syncthreads();
    for (int idx = tid; idx < 4096; idx += 256) {
        int jo = idx & 63; int th2 = idx >> 6; int h = th2 & 3; int t = th2 >> 2;
        float acc = 0.f;
#pragma unroll
        for (int dd = 0; dd < 16; ++dd)
            acc += vv[t * 64 + h * 16 + dd] * out_w[(size_t)jo * 64 + h * 16 + dd];
        v2L[(t * 4 + h) * 64 + jo] = acc;
    }
    {
        int th = tid >> 2, c = tid & 3;
        int t = th >> 2, h = th & 3;
        float acc = 0.f;
#pragma unroll
        for (int dd = h * 16; dd < h * 16 + 16; ++dd) {
            float w = (c == 0) ? qWs[dd] : (c == 1) ? qWs[64 + dd]
                    : (c == 2) ? qWs[128 + dd] : qbs[dd];
            acc += w * kproj[t * 64 + dd];
        }
        Mfold[((size_t)b * 64 + th) * 4 + c] = 0.25f * acc;
    }
    __syncthreads();
    for (int it = tid; it < 512; it += 256) {
        int lane = it & 63, fi = it >> 6;
        int mi = fi >> 1, step = fi & 1;
        int outd = mi * 16 + (lane & 15);
        int th0 = step * 32 + (lane >> 4) * 8;
        uint4 v;
        v.x = f2b_pack(v2L[(th0 + 0) * 64 + outd], v2L[(th0 + 1) * 64 + outd]);
        v.y = f2b_pack(v2L[(th0 + 2) * 64 + outd], v2L[(th0 + 3) * 64 + outd]);
        v.z = f2b_pack(v2L[(th0 + 4) * 64 + outd], v2L[(th0 + 5) * 64 + outd]);
        v.w = f2b_pack(v2L[(th0 + 6) * 64 + outd], v2L[(th0 + 7) * 64 + outd]);
        v2fG[((size_t)b * 8 + fi) * 64 + lane] = v;
    }
}

// ---------------------------------------------------------------------------
// per-edge cross attention, MFMA PV (unchanged from round 5)
// ---------------------------------------------------------------------------
__global__ __launch_bounds__(256)
void k_edge_attn(const float* __restrict__ ps, const int* __restrict__ ei,
                 const float* __restrict__ Mfold, const uint4* __restrict__ v2f,
                 const float* __restrict__ ob,
                 unsigned short* __restrict__ Pf, float* __restrict__ cnt)
{
    __shared__ unsigned attL[4 * 64 * 34];     // 34.8 KB; per-wave 64x34-dword slab
    int tid = threadIdx.x;
    int wave = tid >> 6, lane = tid & 63, q = lane >> 4, c15 = lane & 15;
    int g = blockIdx.x >> 7;                   // 128 blocks per graph
    int e = blockIdx.x * 256 + tid;
    int s = ei[e], d = ei[EE + e];
    atomicAdd(&cnt[d], 1.f);
    float sx = ps[s * 3], sy = ps[s * 3 + 1], sz = ps[s * 3 + 2];
    float dx = ps[d * 3], dy = ps[d * 3 + 1], dz = ps[d * 3 + 2];
    float px = dx - sx, py = dy - sy, pz = dz - sz;
    float ex = 0.5f * (dx + sx), ey = 0.5f * (dy + sy), ez = 0.5f * (dz + sz);

    const float4* Mg = (const float4*)Mfold + (size_t)g * 64;
    float sc[64];
#pragma unroll
    for (int th = 0; th < 64; ++th) {
        float4 m = Mg[th];
        sc[th] = ex * m.x + ey * m.y + ez * m.z + m.w;
    }
#pragma unroll
    for (int h = 0; h < 4; ++h) {
        float mx = sc[h];
#pragma unroll
        for (int t = 1; t < 16; ++t) mx = fmaxf(mx, sc[t * 4 + h]);
        float ssum = 0.f;
#pragma unroll
        for (int t = 0; t < 16; ++t) {
            float eo = expf(sc[t * 4 + h] - mx);
            sc[t * 4 + h] = eo; ssum += eo;
        }
        float inv = 1.f / ssum;
#pragma unroll
        for (int t = 0; t < 16; ++t) sc[t * 4 + h] *= inv;
    }
    unsigned* slab = attL + wave * 64 * 34;
#pragma unroll
    for (int k = 0; k < 16; ++k) {
        uint2 v;
        v.x = f2b_pack(sc[4 * k + 0], sc[4 * k + 1]);
        v.y = f2b_pack(sc[4 * k + 2], sc[4 * k + 3]);
        *(uint2*)&slab[lane * 34 + 2 * k] = v;
    }
    __syncthreads();

    uint4 v2a[4][2];
#pragma unroll
    for (int mi = 0; mi < 4; ++mi)
#pragma unroll
        for (int st = 0; st < 2; ++st)
            v2a[mi][st] = v2f[((size_t)g * 8 + mi * 2 + st) * 64 + lane];

    f32x4 acc[4][4];
#pragma unroll
    for (int mi = 0; mi < 4; ++mi)
#pragma unroll
        for (int nt = 0; nt < 4; ++nt) acc[mi][nt] = (f32x4){0.f, 0.f, 0.f, 0.f};

#pragma unroll
    for (int nt = 0; nt < 4; ++nt) {
        const unsigned* rb = &slab[(nt * 16 + c15) * 34];
        uint4 b0 = *(const uint4*)&rb[q * 4];
        uint4 b1 = *(const uint4*)&rb[16 + q * 4];
#pragma unroll
        for (int mi = 0; mi < 4; ++mi) {
            acc[mi][nt] = __builtin_amdgcn_mfma_f32_16x16x32_bf16(bc8(v2a[mi][0]), bc8(b0), acc[mi][nt], 0, 0, 0);
            acc[mi][nt] = __builtin_amdgcn_mfma_f32_16x16x32_bf16(bc8(v2a[mi][1]), bc8(b1), acc[mi][nt], 0, 0, 0);
        }
    }
    __syncthreads();

    float4 obv[4];
#pragma unroll
    for (int mi = 0; mi < 4; ++mi) obv[mi] = *(const float4*)(ob + mi * 16 + q * 4);
#pragma unroll
    for (int mi = 0; mi < 4; ++mi)
#pragma unroll
        for (int nt = 0; nt < 4; ++nt) {
            f32x4 a = acc[mi][nt];
            uint2 v;
            v.x = f2b_pack(a[0] + obv[mi].x, a[1] + obv[mi].y);
            v.y = f2b_pack(a[2] + obv[mi].z, a[3] + obv[mi].w);
            *(uint2*)&slab[(nt * 16 + c15) * 34 + mi * 8 + q * 2] = v;
        }
    __syncthreads();

    uint4* Pf4 = (uint4*)Pf;
#pragma unroll
    for (int et = 0; et < 4; ++et) {
        int etg = blockIdx.x * 16 + wave * 4 + et;
#pragma unroll
        for (int st = 0; st < 2; ++st) {
            uint4 w = *(const uint4*)&slab[(et * 16 + c15) * 34 + st * 16 + q * 4];
            Pf4[((size_t)etg * 3 + st) * 64 + lane] = w;
        }
    }
    int et2 = e >> 4, eL = e & 15;
    size_t tb = ((size_t)(et2 * 3 + 2) * 64 + 0 * 16 + eL) * 8;
    uint2 t0; t0.x = f2b_pack(px, py); t0.y = f2b_pack(pz, 1.0f);
    *(uint2*)(Pf + tb) = t0;
    uint2 z2; z2.x = 0u; z2.y = 0u;
    *(uint2*)(Pf + tb + 4) = z2;
#pragma unroll
    for (int quad = 1; quad < 4; ++quad) {
        size_t zb = ((size_t)(et2 * 3 + 2) * 64 + quad * 16 + eL) * 8;
        uint4 z4; z4.x = 0u; z4.y = 0u; z4.z = 0u; z4.w = 0u;
        *(uint4*)(Pf + zb) = z4;
    }
}

// ---------------------------------------------------------------------------
// fused repack of all 3 layers' nn_w/nn_b -> bf16 B-fragment streams
// ---------------------------------------------------------------------------
static __device__ inline void repack_one(const float* __restrict__ nw,
                                         const float* __restrict__ nb,
                                         unsigned short* __restrict__ Wf, int idx)
{
    int jj = idx & 7;
    int lane = (idx >> 3) & 63;
    int rest = idx >> 9;
    int s = rest % 3;
    int jt = rest / 3;
    int j = jt * 16 + (lane & 15);
    int k = s * 32 + (lane >> 4) * 8 + jj;
    float v;
    if (k < 64)       v = nw[(size_t)j * 67 + 3 + k];
    else if (k < 67)  v = nw[(size_t)j * 67 + (k - 64)];
    else if (k == 67) v = nb[j];
    else              v = 0.f;
    Wf[idx] = f2b(v);
}

__global__ __launch_bounds__(256)
void k_repackAll(const float* __restrict__ nw0, const float* __restrict__ nb0,
                 const float* __restrict__ nw1, const float* __restrict__ nb1,
                 const float* __restrict__ nw2, const float* __restrict__ nb2,
                 unsigned short* __restrict__ Wf0, unsigned short* __restrict__ Wf1,
                 unsigned short* __restrict__ Wf2)
{
    int idx = blockIdx.x * 256 + threadIdx.x;
    if (idx < 98304)        repack_one(nw0, nb0, Wf0, idx);
    else if (idx < 196608)  repack_one(nw1, nb1, Wf1, idx - 98304);
    else                    repack_one(nw2, nb2, Wf2, idx - 196608);
}

// ---------------------------------------------------------------------------
// MFMA edge pass, split-K wave pairs: block = 256 thr = 2 groups x 2 waves,
// 128 edges/block (grid 1024 -> 4 blocks/CU). For CO=32 the wave pair splits
// the par (output-column-half) dimension -> disjoint outputs, no combine,
// same Wf traffic. For CO=16 the pair splits the i-range; LDS combine
// (stride-17, 2-lane/bank = free), half-0 wave does the atomics.
// ---------------------------------------------------------------------------
template<int CO>
__global__ __launch_bounds__(256, 4)
void k_conv_mfma(const uint4* __restrict__ Pf, const float* __restrict__ hin,
                 const int* __restrict__ ei, const uint4* __restrict__ Wf,
                 float* __restrict__ aggr)
{
    __shared__ float hL[128 * 36];             // 18.4 KB
    __shared__ int sL[128];
    __shared__ int dL[128];
    constexpr int REDSZ = (CO == 16) ? 2 * 64 * 17 : 4;
    __shared__ float red[REDSZ];               // 8.7 KB (CO=16 only)

    int tid = threadIdx.x;
    int e0 = blockIdx.x * 128;
    if (tid < 128) sL[tid] = ei[e0 + tid];
    else           dL[tid - 128] = ei[EE + e0 + (tid - 128)];
    __syncthreads();
    for (int idx = tid; idx < 1024; idx += 256) {
        int row = idx >> 3, c = idx & 7;
        const float4* hr = (const float4*)(hin + (size_t)sL[row] * 32);
        *(float4*)&hL[row * 36 + c * 4] = hr[c];
    }
    __syncthreads();

    int wave = tid >> 6, lane = tid & 63, quad = lane >> 4, col = lane & 15;
    int group = wave >> 1, half = wave & 1;

    uint4 a[4][3];
    int et0 = blockIdx.x * 8 + group * 4;
#pragma unroll
    for (int st = 0; st < 4; ++st)
#pragma unroll
        for (int s = 0; s < 3; ++s)
            a[st][s] = Pf[((size_t)(et0 + st) * 3 + s) * 64 + lane];

    float msg[4][4];
#pragma unroll
    for (int st = 0; st < 4; ++st)
#pragma unroll
        for (int r = 0; r < 4; ++r) msg[st][r] = 0.f;

    int ibase = (CO == 32) ? 0 : half * 16;
    constexpr int NI2 = (CO == 32) ? 16 : 8;   // i-pairs per wave

    for (int i2 = 0; i2 < NI2; ++i2) {
        float2 hv2[4][4];
#pragma unroll
        for (int st = 0; st < 4; ++st)
#pragma unroll
            for (int r = 0; r < 4; ++r)
                hv2[st][r] = *(const float2*)&hL[(group * 64 + st * 16 + quad * 4 + r) * 36
                                                 + ibase + i2 * 2];
#pragma unroll
        for (int ii = 0; ii < 2; ++ii) {
            int i = ibase + i2 * 2 + ii;
            int jt = (CO == 32) ? (i * 2 + half) : i;
            uint4 b0 = Wf[((size_t)jt * 3 + 0) * 64 + lane];
            uint4 b1 = Wf[((size_t)jt * 3 + 1) * 64 + lane];
            uint4 b2 = Wf[((size_t)jt * 3 + 2) * 64 + lane];
#pragma unroll
            for (int st = 0; st < 4; ++st) {
                f32x4 c = {0.f, 0.f, 0.f, 0.f};
                c = __builtin_amdgcn_mfma_f32_16x16x32_bf16(bc8(a[st][0]), bc8(b0), c, 0, 0, 0);
                c = __builtin_amdgcn_mfma_f32_16x16x32_bf16(bc8(a[st][1]), bc8(b1), c, 0, 0, 0);
                c = __builtin_amdgcn_mfma_f32_16x16x32_bf16(bc8(a[st][2]), bc8(b2), c, 0, 0, 0);
#pragma unroll
                for (int r = 0; r < 4; ++r) {
                    float hv = ii ? hv2[st][r].y : hv2[st][r].x;
                    msg[st][r] += hv * fmaxf(c[r], 0.f);
                }
            }
        }
    }

    if (CO == 32) {
        // disjoint output columns per half: no combine needed
#pragma unroll
        for (int st = 0; st < 4; ++st)
#pragma unroll
            for (int r = 0; r < 4; ++r) {
                int dv = dL[group * 64 + st * 16 + quad * 4 + r];
                atomicAdd(&aggr[(size_t)dv * 32 + half * 16 + col], msg[st][r]);
            }
    } else {
        if (half == 1) {
#pragma unroll
            for (int st = 0; st < 4; ++st)
#pragma unroll
                for (int r = 0; r < 4; ++r)
                    red[group * 64 * 17 + lane * 17 + st * 4 + r] = msg[st][r];
        }
        __syncthreads();
        if (half == 0) {
#pragma unroll
            for (int st = 0; st < 4; ++st)
#pragma unroll
                for (int r = 0; r < 4; ++r) {
                    float m = msg[st][r] + red[group * 64 * 17 + lane * 17 + st * 4 + r];
                    int dv = dL[group * 64 + st * 16 + quad * 4 + r];
                    atomicAdd(&aggr[(size_t)dv * 16 + col], m);
                }
        }
    }
}

// ---------------------------------------------------------------------------
// node update: h' = relu(aggr/cnt + h @ root + bias); zeroes aggr for the
// next layer's atomic pass.
// ---------------------------------------------------------------------------
template<int CO>
__global__ __launch_bounds__(256)
void k_update(float* __restrict__ aggr, const float* __restrict__ cnt,
              const float* __restrict__ hin, const float* __restrict__ root,
              const float* __restrict__ bias, float* __restrict__ hout)
{
    __shared__ float rL[32 * CO];
    __shared__ float bL[CO];
    int tid = threadIdx.x;
    for (int idx = tid; idx < 32 * CO; idx += 256) rL[idx] = root[idx];
    if (tid < CO) bL[tid] = bias[tid];
    __syncthreads();
    int gid = blockIdx.x * 256 + tid;
    int v = gid / CO;
    int o = gid % CO;
    float acc = aggr[gid] / fmaxf(cnt[v], 1.f) + bL[o];
    aggr[gid] = 0.f;                    // prep next layer's scatter
    const float* hr = hin + (size_t)v * 32;
#pragma unroll
    for (int i = 0; i < 32; ++i) acc += hr[i] * rL[i * CO + o];
    hout[gid] = fmaxf(acc, 0.f);
}

// ---------------------------------------------------------------------------
extern "C" void kernel_launch(void* const* d_in, const int* in_sizes, int n_in,
                              void* d_out, int out_size, void* d_ws, size_t ws_size,
                              hipStream_t stream)
{
    const float* x          = (const float*)d_in[0];
    const float* pos        = (const float*)d_in[1];
    const float* x_skip     = (const float*)d_in[3];
    const float* pos_skip   = (const float*)d_in[4];
    const int*   batch_skip = (const int*)  d_in[5];
    const int*   ei         = (const int*)  d_in[6];
    const float* gt         = (const float*)d_in[7];
    const float* Wq_w       = (const float*)d_in[8];
    const float* Wq_b       = (const float*)d_in[9];
    const float* Wk_w       = (const float*)d_in[10];
    const float* Wk_b       = (const float*)d_in[11];
    const float* Wv_w       = (const float*)d_in[12];
    const float* Wv_b       = (const float*)d_in[13];
    const float* in_proj_w  = (const float*)d_in[14];
    const float* in_proj_b  = (const float*)d_in[15];
    const float* out_w      = (const float*)d_in[16];
    const float* out_b      = (const float*)d_in[17];
    const float* nn_w0 = (const float*)d_in[18]; const float* nn_b0 = (const float*)d_in[19];
    const float* root0 = (const float*)d_in[20]; const float* bias0 = (const float*)d_in[21];
    const float* nn_w1 = (const float*)d_in[22]; const float* nn_b1 = (const float*)d_in[23];
    const float* root1 = (const float*)d_in[24]; const float* bias1 = (const float*)d_in[25];
    const float* nn_w2 = (const float*)d_in[26]; const float* nn_b2 = (const float*)d_in[27];
    const float* root2 = (const float*)d_in[28]; const float* bias2 = (const float*)d_in[29];

    char* wsb = (char*)d_ws;
    size_t off = 0;
    auto carve = [&](size_t bytes) { char* p = wsb + off; off += (bytes + 255) & ~(size_t)255; return p; };
    float* aggr = (float*)carve((size_t)MM * 32 * 4);   // aggr then cnt: one memset
    float* cnt  = (float*)carve((size_t)MM * 4);
    float* hA   = (float*)carve((size_t)MM * 32 * 4);
    float* hB   = (float*)carve((size_t)MM * 32 * 4);
    unsigned short* Pf  = (unsigned short*)carve((size_t)EE * 96 * 2);
    unsigned short* Wf0 = (unsigned short*)carve((size_t)1024 * 96 * 2);
    unsigned short* Wf1 = (unsigned short*)carve((size_t)1024 * 96 * 2);
    unsigned short* Wf2 = (unsigned short*)carve((size_t)512 * 96 * 2);
    float* Mfold = (float*)carve((size_t)NB * 64 * 4 * 4);
    uint4* v2f   = (uint4*)carve((size_t)NB * 8 * 64 * 16);
    float* KtVt  = (float*)carve((size_t)NB * 2 * 16 * 64 * 4);

    float* h_final   = (float*)d_out;                 // [M,16]
    float* out_pos   = (float*)d_out + (size_t)MM * 16;
    float* out_batch = (float*)d_out + (size_t)MM * 19;

    // one memset covers aggr (MM*32) + cnt (MM) — adjacent carves
    hipMemsetAsync(aggr, 0, ((size_t)MM * 32 + MM) * sizeof(float), stream);

    k_tokens1<<<64, 128, 0, stream>>>(gt, Wk_w, Wk_b, Wv_w, Wv_b, KtVt);
    k_tokens2<<<NB, 256, 0, stream>>>(KtVt, in_proj_w, in_proj_b, out_w, Wq_w, Wq_b,
                                      Mfold, v2f);
    k_knn<<<MM / 64, 256, 0, stream>>>(pos, pos_skip, x, x_skip, batch_skip,
                                       hA, out_pos, out_batch);
    k_edge_attn<<<EE / 256, 256, 0, stream>>>(pos_skip, ei, Mfold, v2f, out_b,
                                              Pf, cnt);
    k_repackAll<<<960, 256, 0, stream>>>(nn_w0, nn_b0, nn_w1, nn_b1, nn_w2, nn_b2,
                                         Wf0, Wf1, Wf2);

    // layer 0: hA -> hB   (update zeroes aggr for layer 1)
    k_conv_mfma<32><<<EE / 128, 256, 0, stream>>>((const uint4*)Pf, hA, ei, (const uint4*)Wf0, aggr);
    k_update<32><<<(MM * 32) / 256, 256, 0, stream>>>(aggr, cnt, hA, root0, bias0, hB);
    // layer 1: hB -> hA   (update zeroes aggr for layer 2)
    k_conv_mfma<32><<<EE / 128, 256, 0, stream>>>((const uint4*)Pf, hB, ei, (const uint4*)Wf1, aggr);
    k_update<32><<<(MM * 32) / 256, 256, 0, stream>>>(aggr, cnt, hB, root1, bias1, hA);
    // layer 2: hA -> d_out
    k_conv_mfma<16><<<EE / 128, 256, 0, stream>>>((const uint4*)Pf, hA, ei, (const uint4*)Wf2, aggr);
    k_update<16><<<(MM * 16) / 256, 256, 0, stream>>>(aggr, cnt, hA, root2, bias2, h_final);
}